// Round 21
// baseline (91.793 us; speedup 1.0000x reference)
//
#include <hip/hip_runtime.h>

#define NN 100000
#define EE 1600000
#define FO 32
#define NBKT 512
#define DPB 196            // dst nodes per bucket; NBKT*DPB = 100352 >= NN
#define RND 6400           // edges per msplit block: EE/RND = 250 blocks exact
#define EPT 25             // edges per thread in msplit (RND/256)
#define LCAP 4096          // per-bucket edge cap (mean 3136, +17 sigma)
#define NTILES 6250        // NN/16 row-tiles for mfma gemm
#define GEMMB 782          // persistent: 3128 waves, ~2 tiles each
#define HISTB 196          // ceil(EE/8192)
#define PSHIFT 17          // src fits in 17 bits (NN < 2^17)
#define PMASK  0x1FFFF

typedef __attribute__((ext_vector_type(8))) short short8;   // 8 bf16
typedef __attribute__((ext_vector_type(4))) float f32x4;

// ---------------- threefry2x32 with key (0,1) = jax.random.key(1) -------
__device__ __forceinline__ unsigned rotl32(unsigned x, unsigned r) {
    return (x << r) | (x >> (32u - r));
}

__device__ __forceinline__ void threefry2x32_01(unsigned x0, unsigned x1,
                                                unsigned& y0, unsigned& y1) {
    const unsigned ks0 = 0u, ks1 = 1u, ks2 = 0x1BD11BDBu;
    x0 += ks0; x1 += ks1;
#define TF_R(r) { x0 += x1; x1 = rotl32(x1, (r)); x1 ^= x0; }
    TF_R(13) TF_R(15) TF_R(26) TF_R(6)   x0 += ks1; x1 += ks2 + 1u;
    TF_R(17) TF_R(29) TF_R(16) TF_R(24)  x0 += ks2; x1 += ks0 + 2u;
    TF_R(13) TF_R(15) TF_R(26) TF_R(6)   x0 += ks0; x1 += ks1 + 3u;
    TF_R(17) TF_R(29) TF_R(16) TF_R(24)  x0 += ks1; x1 += ks2 + 4u;
    TF_R(13) TF_R(15) TF_R(26) TF_R(6)   x0 += ks2; x1 += ks0 + 5u;
#undef TF_R
    y0 = x0; y1 = x1;
}

__device__ __forceinline__ unsigned short f2bf(float f) {   // RNE
    unsigned u = __float_as_uint(f);
    unsigned r = (u + 0x7fffu + ((u >> 16) & 1u)) >> 16;
    return (unsigned short)r;
}
__device__ __forceinline__ float bf2f(unsigned short b) {
    return __uint_as_float(((unsigned)b) << 16);
}

// ---------------- K_setup: detect + zero bhist/gcursor + W->bf16^T ------
__global__ __launch_bounds__(256) void k_setup(
    const unsigned* __restrict__ ei, const float* __restrict__ W,
    unsigned* __restrict__ flag, int* __restrict__ bhist,
    int* __restrict__ gcursor, unsigned short* __restrict__ Wt16)
{
    __shared__ unsigned red[256];
    const int tid = threadIdx.x;
    for (int i = tid; i < NBKT; i += 256) { bhist[i] = 0; gcursor[i] = 0; }
    for (int i = tid; i < 32 * 256; i += 256) {     // Wt16[n][k] = bf16(W[k][n])
        int n = i >> 8, k = i & 255;
        Wt16[i] = f2bf(W[k * 32 + n]);
    }
    unsigned v = 0;
    for (int i = tid; i < 4096; i += 256) v |= ei[2 * i + 1];
    red[tid] = v;
    __syncthreads();
    for (int s = 128; s; s >>= 1) {
        if (tid < s) red[tid] |= red[tid + s];
        __syncthreads();
    }
    if (tid == 0) *flag = (red[0] == 0u) ? 1u : 0u;  // 1 => int64
}

__device__ __forceinline__ int load_idx(const int* __restrict__ ei,
                                        int logical, unsigned wide) {
    return ei[wide ? (logical << 1) : logical];
}

// ---------------- K1: persistent MFMA GEMM (rotated pipeline) + hist ----
__global__ __launch_bounds__(256) void k_gemm_hist(
    const float* __restrict__ x, const unsigned short* __restrict__ Wt16,
    const float* __restrict__ att_s, const float* __restrict__ att_d,
    unsigned short* __restrict__ h16,
    float* __restrict__ a_s, float* __restrict__ a_d,
    const int* __restrict__ ei, const unsigned* __restrict__ flag,
    int* __restrict__ bhist)
{
    __shared__ int hl[NBKT];
    if (blockIdx.x < GEMMB) {
        const int lane = threadIdx.x & 63;
        const int wid  = threadIdx.x >> 6;
        const int c = lane & 15;
        const int g = lane >> 4;

        short8 bfrag[8][2];                 // hoisted: once per wave
        #pragma unroll
        for (int kt = 0; kt < 8; ++kt)
            #pragma unroll
            for (int nt = 0; nt < 2; ++nt)
                bfrag[kt][nt] = *reinterpret_cast<const short8*>(
                    Wt16 + (nt * 16 + c) * 256 + kt * 32 + g * 8);

        const float s0 = att_s[c], s1 = att_s[c + 16];
        const float t0 = att_d[c], t1 = att_d[c + 16];
        const int wstride = GEMMB * 4;

        int tile = blockIdx.x * 4 + wid;
        if (tile < NTILES) {
            float4 xv[8][2];
            // prologue: issue tile-0 loads
            {
                const float* xrow = x + (size_t)(tile * 16 + c) * 256 + g * 8;
                #pragma unroll
                for (int kt = 0; kt < 8; ++kt) {
                    xv[kt][0] = *reinterpret_cast<const float4*>(xrow + kt * 32);
                    xv[kt][1] = *reinterpret_cast<const float4*>(xrow + kt * 32 + 4);
                }
            }
            while (true) {
                const int next = tile + wstride;
                __builtin_amdgcn_sched_barrier(0);   // loads stay above compute

                f32x4 acc0 = {0.f, 0.f, 0.f, 0.f};
                f32x4 acc1 = {0.f, 0.f, 0.f, 0.f};
                #pragma unroll
                for (int kt = 0; kt < 8; ++kt) {
                    float4 xa = xv[kt][0], xb = xv[kt][1];
                    short8 af;
                    af[0] = (short)f2bf(xa.x); af[1] = (short)f2bf(xa.y);
                    af[2] = (short)f2bf(xa.z); af[3] = (short)f2bf(xa.w);
                    af[4] = (short)f2bf(xb.x); af[5] = (short)f2bf(xb.y);
                    af[6] = (short)f2bf(xb.z); af[7] = (short)f2bf(xb.w);
                    acc0 = __builtin_amdgcn_mfma_f32_16x16x32_bf16(af, bfrag[kt][0], acc0, 0, 0, 0);
                    acc1 = __builtin_amdgcn_mfma_f32_16x16x32_bf16(af, bfrag[kt][1], acc1, 0, 0, 0);
                }
                // xv dead: issue NEXT tile's loads now; latency hides under
                // the epilogue below + next iteration's convert-wait.
                if (next < NTILES) {
                    const float* xrow = x + (size_t)(next * 16 + c) * 256 + g * 8;
                    #pragma unroll
                    for (int kt = 0; kt < 8; ++kt) {
                        xv[kt][0] = *reinterpret_cast<const float4*>(xrow + kt * 32);
                        xv[kt][1] = *reinterpret_cast<const float4*>(xrow + kt * 32 + 4);
                    }
                }
                __builtin_amdgcn_sched_barrier(0);   // pin loads above epilogue

                const int row0 = tile * 16;
                #pragma unroll
                for (int q = 0; q < 4; ++q) {
                    const int row = row0 + g * 4 + q;
                    h16[(size_t)row * 32 + c]      = f2bf(acc0[q]);
                    h16[(size_t)row * 32 + 16 + c] = f2bf(acc1[q]);
                    float v1 = acc0[q] * s0 + acc1[q] * s1;
                    float v2 = acc0[q] * t0 + acc1[q] * t1;
                    #pragma unroll
                    for (int off = 8; off; off >>= 1) {
                        v1 += __shfl_xor(v1, off, 16);
                        v2 += __shfl_xor(v2, off, 16);
                    }
                    if (c == 0) { a_s[row] = v1; a_d[row] = v2; }
                }
                if (next >= NTILES) break;
                tile = next;
            }
        }
    } else {
        const int tid = threadIdx.x;
        for (int i = tid; i < NBKT; i += 256) hl[i] = 0;
        __syncthreads();
        const unsigned wide = *flag;
        const int base = (blockIdx.x - GEMMB) * 8192;
        #pragma unroll
        for (int k = 0; k < 32; ++k) {
            int e = base + k * 256 + tid;
            if (e < EE) {
                unsigned d = (unsigned)load_idx(ei, EE + e, wide);
                atomicAdd(&hl[d / DPB], 1);
            }
        }
        __syncthreads();
        for (int i = tid; i < NBKT; i += 256)
            if (hl[i]) atomicAdd(&bhist[i], hl[i]);
    }
}

// ---------------- K_C: multisplit, single ei pass (regs), 250 blocks ----
__global__ __launch_bounds__(256) void k_msplit(
    const int* __restrict__ ei, const unsigned* __restrict__ flag,
    const int* __restrict__ bhist, int* __restrict__ gcursor,
    unsigned* __restrict__ packed)
{
    __shared__ int2 staged[RND];       // 51.2 KB
    __shared__ int hist[NBKT], base[NBKT], rcnt[NBKT], gposL[NBKT];
    __shared__ int boffsL[NBKT];
    __shared__ int pair[256];
    const int tid = threadIdx.x;
    const int chunk0 = blockIdx.x * RND;
    const unsigned wide = *flag;

    // local exclusive scan of global bhist -> boffsL (replaces k_scan)
    {
        int c0 = bhist[2 * tid], c1 = bhist[2 * tid + 1];
        pair[tid] = c0 + c1;
        __syncthreads();
        for (int off = 1; off < 256; off <<= 1) {
            int add = (tid >= off) ? pair[tid - off] : 0;
            __syncthreads();
            pair[tid] += add;
            __syncthreads();
        }
        int excl = pair[tid] - c0 - c1;
        boffsL[2 * tid] = excl;
        boffsL[2 * tid + 1] = excl + c0;
    }
    for (int i = tid; i < NBKT; i += 256) { hist[i] = 0; rcnt[i] = 0; }
    __syncthreads();
    // pass 1: read s,d ONCE into registers (exact tiling: no bounds checks),
    // histogram from registers
    int sreg[EPT], dreg[EPT];
    #pragma unroll
    for (int k = 0; k < EPT; ++k) {
        int e = chunk0 + k * 256 + tid;
        sreg[k] = load_idx(ei, e, wide);
        dreg[k] = load_idx(ei, EE + e, wide);
        atomicAdd(&hist[(unsigned)dreg[k] / DPB], 1);
    }
    __syncthreads();
    int h0 = hist[2 * tid], h1 = hist[2 * tid + 1];
    pair[tid] = h0 + h1;
    __syncthreads();
    for (int off = 1; off < 256; off <<= 1) {
        int add = (tid >= off) ? pair[tid - off] : 0;
        __syncthreads();
        pair[tid] += add;
        __syncthreads();
    }
    int excl = pair[tid] - h0 - h1;
    base[2 * tid] = excl;
    base[2 * tid + 1] = excl + h0;
    for (int b = tid; b < NBKT; b += 256) {
        int c = hist[b];
        if (c) gposL[b] = boffsL[b] + atomicAdd(&gcursor[b], c);
    }
    __syncthreads();
    // pass 2: place from registers into bucket-sorted LDS
    #pragma unroll
    for (int k = 0; k < EPT; ++k) {
        int b = (unsigned)dreg[k] / DPB;
        int lp = base[b] + atomicAdd(&rcnt[b], 1);
        staged[lp] = make_int2(sreg[k], dreg[k]);
    }
    __syncthreads();
    for (int i = tid; i < RND; i += 256) {
        int2 ed = staged[i];
        unsigned b = (unsigned)ed.y / DPB;
        unsigned nl = (unsigned)ed.y - b * DPB;
        packed[gposL[b] + (i - base[b])] = (nl << PSHIFT) | (unsigned)ed.x;
    }
}

// ---------------- K_D: bucket sort + aggregate (4 cols/lane) ------------
__global__ __launch_bounds__(1024) void k_aggr(
    const unsigned* __restrict__ packed, const int* __restrict__ bhist,
    const unsigned short* __restrict__ h16,
    const float* __restrict__ a_s, const float* __restrict__ a_d,
    const float* __restrict__ bias, float* __restrict__ out)
{
    __shared__ unsigned sraw[LCAP];    // 16 KB raw staged edges
    __shared__ int srt[LCAP];          // 16 KB sorted src ids
    __shared__ int cntL[DPB];
    __shared__ int cur[DPB];
    __shared__ int sc[256];
    __shared__ int gb01[2];
    const int tid = threadIdx.x;
    const int b = blockIdx.x;
    const int d0 = b * DPB;
    int cnt = NN - d0; if (cnt > DPB) cnt = DPB;
    if (cnt <= 0) return;

    // local exclusive scan of bhist -> this bucket's [gb0, gb1)
    int c0 = 0, c1 = 0;
    if (tid < 256) {
        c0 = bhist[2 * tid]; c1 = bhist[2 * tid + 1];
        sc[tid] = c0 + c1;
    }
    __syncthreads();
    for (int off = 1; off < 256; off <<= 1) {
        int add = (tid < 256 && tid >= off) ? sc[tid - off] : 0;
        __syncthreads();
        if (tid < 256) sc[tid] += add;
        __syncthreads();
    }
    if (tid == (b >> 1)) {
        int excl = sc[tid] - c0 - c1;
        if (b & 1) { gb01[0] = excl + c0; gb01[1] = excl + c0 + c1; }
        else       { gb01[0] = excl;      gb01[1] = excl + c0; }
    }
    __syncthreads();
    const int gb0 = gb01[0];
    int m = gb01[1] - gb0; if (m > LCAP) m = LCAP;

    if (tid < DPB) cntL[tid] = 0;
    __syncthreads();
    for (int i = tid; i < m; i += 1024) {               // pass 1: stage+count
        unsigned p = packed[gb0 + i];
        sraw[i] = p;
        atomicAdd(&cntL[p >> PSHIFT], 1);
    }
    __syncthreads();
    if (tid < 256) sc[tid] = (tid < cnt) ? cntL[tid] : 0;
    __syncthreads();
    for (int off = 1; off < 256; off <<= 1) {           // Hillis-Steele
        int add = (tid < 256 && tid >= off) ? sc[tid - off] : 0;
        __syncthreads();
        if (tid < 256) sc[tid] += add;
        __syncthreads();
    }
    if (tid < cnt) cur[tid] = sc[tid] - cntL[tid];      // exclusive start
    __syncthreads();
    for (int i = tid; i < m; i += 1024) {               // pass 2: place (LDS)
        unsigned p = sraw[i];
        int pos = atomicAdd(&cur[p >> PSHIFT], 1);
        srt[pos] = (int)(p & PMASK);
    }
    __syncthreads();
    // aggregation: 8-lane group per node; lane j4 owns cols 4j4..4j4+3
    const int grp = tid >> 3;          // 0..127
    const int j4  = tid & 7;
#define HLOAD(sid) *reinterpret_cast<const uint2*>(h16 + (size_t)(sid) * 32 + 4 * j4)
#define UNLO(u) __uint_as_float((u) << 16)
#define UNHI(u) __uint_as_float((u) & 0xffff0000u)
    for (int nl = grp; nl < cnt; nl += 128) {
        const int d = d0 + nl;
        const float ad = a_d[d];
        const int e0 = (nl == 0) ? 0 : cur[nl - 1];
        const int e1 = cur[nl];
        float a0 = 0.f, a1 = 0.f, a2 = 0.f, a3 = 0.f, den = 0.f;
        int i = e0;
        for (; i + 3 < e1; i += 4) {                    // unroll-4 for MLP
            int s1 = srt[i], s2 = srt[i+1], s3 = srt[i+2], s4 = srt[i+3];
            uint2 u1 = HLOAD(s1), u2 = HLOAD(s2), u3 = HLOAD(s3), u4 = HLOAD(s4);
            float al1 = a_s[s1] + ad, al2 = a_s[s2] + ad;
            float al3 = a_s[s3] + ad, al4 = a_s[s4] + ad;
            al1 = (al1 >= 0.f) ? al1 : 0.2f * al1;
            al2 = (al2 >= 0.f) ? al2 : 0.2f * al2;
            al3 = (al3 >= 0.f) ? al3 : 0.2f * al3;
            al4 = (al4 >= 0.f) ? al4 : 0.2f * al4;
            float w1 = __expf(al1), w2 = __expf(al2);
            float w3 = __expf(al3), w4 = __expf(al4);
            a0 = fmaf(w1, UNLO(u1.x), a0); a1 = fmaf(w1, UNHI(u1.x), a1);
            a2 = fmaf(w1, UNLO(u1.y), a2); a3 = fmaf(w1, UNHI(u1.y), a3); den += w1;
            a0 = fmaf(w2, UNLO(u2.x), a0); a1 = fmaf(w2, UNHI(u2.x), a1);
            a2 = fmaf(w2, UNLO(u2.y), a2); a3 = fmaf(w2, UNHI(u2.y), a3); den += w2;
            a0 = fmaf(w3, UNLO(u3.x), a0); a1 = fmaf(w3, UNHI(u3.x), a1);
            a2 = fmaf(w3, UNLO(u3.y), a2); a3 = fmaf(w3, UNHI(u3.y), a3); den += w3;
            a0 = fmaf(w4, UNLO(u4.x), a0); a1 = fmaf(w4, UNHI(u4.x), a1);
            a2 = fmaf(w4, UNLO(u4.y), a2); a3 = fmaf(w4, UNHI(u4.y), a3); den += w4;
        }
        for (; i < e1; ++i) {
            int s1 = srt[i];
            uint2 u1 = HLOAD(s1);
            float al1 = a_s[s1] + ad;
            al1 = (al1 >= 0.f) ? al1 : 0.2f * al1;
            float w1 = __expf(al1);
            a0 = fmaf(w1, UNLO(u1.x), a0); a1 = fmaf(w1, UNHI(u1.x), a1);
            a2 = fmaf(w1, UNLO(u1.y), a2); a3 = fmaf(w1, UNHI(u1.y), a3); den += w1;
        }
        // self-loop
        {
            uint2 u1 = HLOAD(d);
            float al = a_s[d] + ad;
            al = (al >= 0.f) ? al : 0.2f * al;
            float w = __expf(al);
            a0 = fmaf(w, UNLO(u1.x), a0); a1 = fmaf(w, UNHI(u1.x), a1);
            a2 = fmaf(w, UNLO(u1.y), a2); a3 = fmaf(w, UNHI(u1.y), a3); den += w;
        }
        // fused epilogue: /den + bias + relu + threefry dropout, float4 store
        const int t = d * 32 + 4 * j4;
        float rd = 1.0f / den;
        float v0 = fmaxf(a0 * rd + bias[4 * j4],     0.f);
        float v1 = fmaxf(a1 * rd + bias[4 * j4 + 1], 0.f);
        float v2 = fmaxf(a2 * rd + bias[4 * j4 + 2], 0.f);
        float v3 = fmaxf(a3 * rd + bias[4 * j4 + 3], 0.f);
        unsigned p0, q0, p1, q1, p2, q2, p3, q3;
        threefry2x32_01(0u, (unsigned)t,     p0, q0);
        threefry2x32_01(0u, (unsigned)(t+1), p1, q1);
        threefry2x32_01(0u, (unsigned)(t+2), p2, q2);
        threefry2x32_01(0u, (unsigned)(t+3), p3, q3);
        float4 o;
        o.x = ((p0 ^ q0) >> 31) ? 0.f : v0 * 2.f;
        o.y = ((p1 ^ q1) >> 31) ? 0.f : v1 * 2.f;
        o.z = ((p2 ^ q2) >> 31) ? 0.f : v2 * 2.f;
        o.w = ((p3 ^ q3) >> 31) ? 0.f : v3 * 2.f;
        *reinterpret_cast<float4*>(out + t) = o;
    }
#undef HLOAD
#undef UNLO
#undef UNHI
}

extern "C" void kernel_launch(void* const* d_in, const int* in_sizes, int n_in,
                              void* d_out, int out_size, void* d_ws, size_t ws_size,
                              hipStream_t stream) {
    const float* x     = (const float*)d_in[0];
    const float* W     = (const float*)d_in[1];
    const float* att_s = (const float*)d_in[2];
    const float* att_d = (const float*)d_in[3];
    const float* bias  = (const float*)d_in[4];
    const int*   ei    = (const int*)d_in[5];
    float* out = (float*)d_out;

    // ws: Wt16[8192] ushort | packed[EE] uint | h16[NN*32] bf16
    //     | a_s[NN] | a_d[NN] | bhist[512] | gcursor[512] | flag
    unsigned short* Wt16 = (unsigned short*)d_ws;
    unsigned* packed = (unsigned*)(Wt16 + 8192);
    unsigned short* h16 = (unsigned short*)(packed + EE);
    float* a_s = (float*)(h16 + (size_t)NN * FO);
    float* a_d = a_s + NN;
    int* bhist = (int*)(a_d + NN);
    int* gcursor = bhist + NBKT;
    unsigned* flag = (unsigned*)(gcursor + NBKT);

    k_setup<<<1, 256, 0, stream>>>((const unsigned*)ei, W, flag, bhist, gcursor, Wt16);
    k_gemm_hist<<<GEMMB + HISTB, 256, 0, stream>>>(
        x, Wt16, att_s, att_d, h16, a_s, a_d, ei, flag, bhist);
    k_msplit<<<EE / RND, 256, 0, stream>>>(ei, flag, bhist, gcursor, packed);
    k_aggr<<<(NN + DPB - 1) / DPB, 1024, 0, stream>>>(packed, bhist, h16, a_s, a_d, bias, out);
}

// Round 22
// 90.449 us; speedup vs baseline: 1.0149x; 1.0149x over previous
//
#include <hip/hip_runtime.h>

#define NN 100000
#define EE 1600000
#define FO 32
#define NBKT 512
#define DPB 196            // dst nodes per bucket; NBKT*DPB = 100352 >= NN
#define RND 6400           // edges per msplit block: EE/RND = 250 blocks exact
#define EPT 25             // edges per thread in msplit (RND/256)
#define LCAP 4096          // per-bucket edge cap (mean 3136, +17 sigma)
#define NTILES 6250        // NN/16 row-tiles for mfma gemm
#define GEMMB 782          // persistent: 3128 waves, ~2 tiles each
#define HISTB 196          // ceil(EE/8192)
#define PSHIFT 17          // src fits in 17 bits (NN < 2^17)
#define PMASK  0x1FFFF

typedef __attribute__((ext_vector_type(8))) short short8;   // 8 bf16
typedef __attribute__((ext_vector_type(4))) float f32x4;

// ---------------- threefry2x32 with key (0,1) = jax.random.key(1) -------
__device__ __forceinline__ unsigned rotl32(unsigned x, unsigned r) {
    return (x << r) | (x >> (32u - r));
}

__device__ __forceinline__ void threefry2x32_01(unsigned x0, unsigned x1,
                                                unsigned& y0, unsigned& y1) {
    const unsigned ks0 = 0u, ks1 = 1u, ks2 = 0x1BD11BDBu;
    x0 += ks0; x1 += ks1;
#define TF_R(r) { x0 += x1; x1 = rotl32(x1, (r)); x1 ^= x0; }
    TF_R(13) TF_R(15) TF_R(26) TF_R(6)   x0 += ks1; x1 += ks2 + 1u;
    TF_R(17) TF_R(29) TF_R(16) TF_R(24)  x0 += ks2; x1 += ks0 + 2u;
    TF_R(13) TF_R(15) TF_R(26) TF_R(6)   x0 += ks0; x1 += ks1 + 3u;
    TF_R(17) TF_R(29) TF_R(16) TF_R(24)  x0 += ks1; x1 += ks2 + 4u;
    TF_R(13) TF_R(15) TF_R(26) TF_R(6)   x0 += ks2; x1 += ks0 + 5u;
#undef TF_R
    y0 = x0; y1 = x1;
}

__device__ __forceinline__ unsigned short f2bf(float f) {   // RNE
    unsigned u = __float_as_uint(f);
    unsigned r = (u + 0x7fffu + ((u >> 16) & 1u)) >> 16;
    return (unsigned short)r;
}
__device__ __forceinline__ float bf2f(unsigned short b) {
    return __uint_as_float(((unsigned)b) << 16);
}

// ---------------- K_setup: detect + zero bhist/gcursor + W->bf16^T ------
__global__ __launch_bounds__(256) void k_setup(
    const unsigned* __restrict__ ei, const float* __restrict__ W,
    unsigned* __restrict__ flag, int* __restrict__ bhist,
    int* __restrict__ gcursor, unsigned short* __restrict__ Wt16)
{
    __shared__ unsigned red[256];
    const int tid = threadIdx.x;
    for (int i = tid; i < NBKT; i += 256) { bhist[i] = 0; gcursor[i] = 0; }
    for (int i = tid; i < 32 * 256; i += 256) {     // Wt16[n][k] = bf16(W[k][n])
        int n = i >> 8, k = i & 255;
        Wt16[i] = f2bf(W[k * 32 + n]);
    }
    unsigned v = 0;
    for (int i = tid; i < 4096; i += 256) v |= ei[2 * i + 1];
    red[tid] = v;
    __syncthreads();
    for (int s = 128; s; s >>= 1) {
        if (tid < s) red[tid] |= red[tid + s];
        __syncthreads();
    }
    if (tid == 0) *flag = (red[0] == 0u) ? 1u : 0u;  // 1 => int64
}

__device__ __forceinline__ int load_idx(const int* __restrict__ ei,
                                        int logical, unsigned wide) {
    return ei[wide ? (logical << 1) : logical];
}

// ---------------- K1: persistent MFMA GEMM + bucket hist ---------------
__global__ __launch_bounds__(256) void k_gemm_hist(
    const float* __restrict__ x, const unsigned short* __restrict__ Wt16,
    const float* __restrict__ att_s, const float* __restrict__ att_d,
    unsigned short* __restrict__ h16,
    float* __restrict__ a_s, float* __restrict__ a_d,
    const int* __restrict__ ei, const unsigned* __restrict__ flag,
    int* __restrict__ bhist)
{
    __shared__ int hl[NBKT];
    if (blockIdx.x < GEMMB) {
        const int lane = threadIdx.x & 63;
        const int wid  = threadIdx.x >> 6;
        const int c = lane & 15;
        const int g = lane >> 4;

        short8 bfrag[8][2];                 // hoisted: once per wave
        #pragma unroll
        for (int kt = 0; kt < 8; ++kt)
            #pragma unroll
            for (int nt = 0; nt < 2; ++nt)
                bfrag[kt][nt] = *reinterpret_cast<const short8*>(
                    Wt16 + (nt * 16 + c) * 256 + kt * 32 + g * 8);

        const float s0 = att_s[c], s1 = att_s[c + 16];
        const float t0 = att_d[c], t1 = att_d[c + 16];
        const int wglobal = blockIdx.x * 4 + wid;
        const int wstride = GEMMB * 4;

        for (int tile = wglobal; tile < NTILES; tile += wstride) {
            const int row0 = tile * 16;
            const float* xrow = x + (size_t)(row0 + c) * 256 + g * 8;

            float4 xv[8][2];
            #pragma unroll
            for (int kt = 0; kt < 8; ++kt) {
                xv[kt][0] = *reinterpret_cast<const float4*>(xrow + kt * 32);
                xv[kt][1] = *reinterpret_cast<const float4*>(xrow + kt * 32 + 4);
            }
            __builtin_amdgcn_sched_barrier(0);   // keep load cluster intact

            f32x4 acc0 = {0.f, 0.f, 0.f, 0.f};
            f32x4 acc1 = {0.f, 0.f, 0.f, 0.f};
            #pragma unroll
            for (int kt = 0; kt < 8; ++kt) {
                float4 xa = xv[kt][0], xb = xv[kt][1];
                short8 af;
                af[0] = (short)f2bf(xa.x); af[1] = (short)f2bf(xa.y);
                af[2] = (short)f2bf(xa.z); af[3] = (short)f2bf(xa.w);
                af[4] = (short)f2bf(xb.x); af[5] = (short)f2bf(xb.y);
                af[6] = (short)f2bf(xb.z); af[7] = (short)f2bf(xb.w);
                acc0 = __builtin_amdgcn_mfma_f32_16x16x32_bf16(af, bfrag[kt][0], acc0, 0, 0, 0);
                acc1 = __builtin_amdgcn_mfma_f32_16x16x32_bf16(af, bfrag[kt][1], acc1, 0, 0, 0);
            }

            #pragma unroll
            for (int q = 0; q < 4; ++q) {
                const int row = row0 + g * 4 + q;
                h16[(size_t)row * 32 + c]      = f2bf(acc0[q]);
                h16[(size_t)row * 32 + 16 + c] = f2bf(acc1[q]);
                float v1 = acc0[q] * s0 + acc1[q] * s1;
                float v2 = acc0[q] * t0 + acc1[q] * t1;
                #pragma unroll
                for (int off = 8; off; off >>= 1) {
                    v1 += __shfl_xor(v1, off, 16);
                    v2 += __shfl_xor(v2, off, 16);
                }
                if (c == 0) { a_s[row] = v1; a_d[row] = v2; }
            }
        }
    } else {
        const int tid = threadIdx.x;
        for (int i = tid; i < NBKT; i += 256) hl[i] = 0;
        __syncthreads();
        const unsigned wide = *flag;
        const int base = (blockIdx.x - GEMMB) * 8192;
        #pragma unroll
        for (int k = 0; k < 32; ++k) {
            int e = base + k * 256 + tid;
            if (e < EE) {
                unsigned d = (unsigned)load_idx(ei, EE + e, wide);
                atomicAdd(&hl[d / DPB], 1);
            }
        }
        __syncthreads();
        for (int i = tid; i < NBKT; i += 256)
            if (hl[i]) atomicAdd(&bhist[i], hl[i]);
    }
}

// ---------------- K_C: multisplit, single ei pass (regs), 250 blocks ----
__global__ __launch_bounds__(256) void k_msplit(
    const int* __restrict__ ei, const unsigned* __restrict__ flag,
    const int* __restrict__ bhist, int* __restrict__ gcursor,
    unsigned* __restrict__ packed)
{
    __shared__ int2 staged[RND];       // 51.2 KB
    __shared__ int hist[NBKT], base[NBKT], rcnt[NBKT], gposL[NBKT];
    __shared__ int boffsL[NBKT];
    __shared__ int pair[256];
    const int tid = threadIdx.x;
    const int chunk0 = blockIdx.x * RND;
    const unsigned wide = *flag;

    // local exclusive scan of global bhist -> boffsL (replaces k_scan)
    {
        int c0 = bhist[2 * tid], c1 = bhist[2 * tid + 1];
        pair[tid] = c0 + c1;
        __syncthreads();
        for (int off = 1; off < 256; off <<= 1) {
            int add = (tid >= off) ? pair[tid - off] : 0;
            __syncthreads();
            pair[tid] += add;
            __syncthreads();
        }
        int excl = pair[tid] - c0 - c1;
        boffsL[2 * tid] = excl;
        boffsL[2 * tid + 1] = excl + c0;
    }
    for (int i = tid; i < NBKT; i += 256) { hist[i] = 0; rcnt[i] = 0; }
    __syncthreads();
    // pass 1: read s,d ONCE into registers (exact tiling: no bounds checks),
    // histogram from registers
    int sreg[EPT], dreg[EPT];
    #pragma unroll
    for (int k = 0; k < EPT; ++k) {
        int e = chunk0 + k * 256 + tid;
        sreg[k] = load_idx(ei, e, wide);
        dreg[k] = load_idx(ei, EE + e, wide);
        atomicAdd(&hist[(unsigned)dreg[k] / DPB], 1);
    }
    __syncthreads();
    int h0 = hist[2 * tid], h1 = hist[2 * tid + 1];
    pair[tid] = h0 + h1;
    __syncthreads();
    for (int off = 1; off < 256; off <<= 1) {
        int add = (tid >= off) ? pair[tid - off] : 0;
        __syncthreads();
        pair[tid] += add;
        __syncthreads();
    }
    int excl = pair[tid] - h0 - h1;
    base[2 * tid] = excl;
    base[2 * tid + 1] = excl + h0;
    for (int b = tid; b < NBKT; b += 256) {
        int c = hist[b];
        if (c) gposL[b] = boffsL[b] + atomicAdd(&gcursor[b], c);
    }
    __syncthreads();
    // pass 2: place from registers into bucket-sorted LDS
    #pragma unroll
    for (int k = 0; k < EPT; ++k) {
        int b = (unsigned)dreg[k] / DPB;
        int lp = base[b] + atomicAdd(&rcnt[b], 1);
        staged[lp] = make_int2(sreg[k], dreg[k]);
    }
    __syncthreads();
    for (int i = tid; i < RND; i += 256) {
        int2 ed = staged[i];
        unsigned b = (unsigned)ed.y / DPB;
        unsigned nl = (unsigned)ed.y - b * DPB;
        packed[gposL[b] + (i - base[b])] = (nl << PSHIFT) | (unsigned)ed.x;
    }
}

// ---------------- K_D: bucket sort + aggregate (4 cols/lane) ------------
__global__ __launch_bounds__(1024) void k_aggr(
    const unsigned* __restrict__ packed, const int* __restrict__ bhist,
    const unsigned short* __restrict__ h16,
    const float* __restrict__ a_s, const float* __restrict__ a_d,
    const float* __restrict__ bias, float* __restrict__ out)
{
    __shared__ unsigned sraw[LCAP];    // 16 KB raw staged edges
    __shared__ int srt[LCAP];          // 16 KB sorted src ids
    __shared__ int cntL[DPB];
    __shared__ int cur[DPB];
    __shared__ int sc[256];
    __shared__ int gb01[2];
    const int tid = threadIdx.x;
    const int b = blockIdx.x;
    const int d0 = b * DPB;
    int cnt = NN - d0; if (cnt > DPB) cnt = DPB;
    if (cnt <= 0) return;

    // local exclusive scan of bhist -> this bucket's [gb0, gb1)
    int c0 = 0, c1 = 0;
    if (tid < 256) {
        c0 = bhist[2 * tid]; c1 = bhist[2 * tid + 1];
        sc[tid] = c0 + c1;
    }
    __syncthreads();
    for (int off = 1; off < 256; off <<= 1) {
        int add = (tid < 256 && tid >= off) ? sc[tid - off] : 0;
        __syncthreads();
        if (tid < 256) sc[tid] += add;
        __syncthreads();
    }
    if (tid == (b >> 1)) {
        int excl = sc[tid] - c0 - c1;
        if (b & 1) { gb01[0] = excl + c0; gb01[1] = excl + c0 + c1; }
        else       { gb01[0] = excl;      gb01[1] = excl + c0; }
    }
    __syncthreads();
    const int gb0 = gb01[0];
    int m = gb01[1] - gb0; if (m > LCAP) m = LCAP;

    if (tid < DPB) cntL[tid] = 0;
    __syncthreads();
    for (int i = tid; i < m; i += 1024) {               // pass 1: stage+count
        unsigned p = packed[gb0 + i];
        sraw[i] = p;
        atomicAdd(&cntL[p >> PSHIFT], 1);
    }
    __syncthreads();
    if (tid < 256) sc[tid] = (tid < cnt) ? cntL[tid] : 0;
    __syncthreads();
    for (int off = 1; off < 256; off <<= 1) {           // Hillis-Steele
        int add = (tid < 256 && tid >= off) ? sc[tid - off] : 0;
        __syncthreads();
        if (tid < 256) sc[tid] += add;
        __syncthreads();
    }
    if (tid < cnt) cur[tid] = sc[tid] - cntL[tid];      // exclusive start
    __syncthreads();
    for (int i = tid; i < m; i += 1024) {               // pass 2: place (LDS)
        unsigned p = sraw[i];
        int pos = atomicAdd(&cur[p >> PSHIFT], 1);
        srt[pos] = (int)(p & PMASK);
    }
    __syncthreads();
    // aggregation: 8-lane group per node; lane j4 owns cols 4j4..4j4+3
    const int grp = tid >> 3;          // 0..127
    const int j4  = tid & 7;
#define HLOAD(sid) *reinterpret_cast<const uint2*>(h16 + (size_t)(sid) * 32 + 4 * j4)
#define UNLO(u) __uint_as_float((u) << 16)
#define UNHI(u) __uint_as_float((u) & 0xffff0000u)
    for (int nl = grp; nl < cnt; nl += 128) {
        const int d = d0 + nl;
        const float ad = a_d[d];
        const int e0 = (nl == 0) ? 0 : cur[nl - 1];
        const int e1 = cur[nl];
        float a0 = 0.f, a1 = 0.f, a2 = 0.f, a3 = 0.f, den = 0.f;
        int i = e0;
        for (; i + 3 < e1; i += 4) {                    // unroll-4 for MLP
            int s1 = srt[i], s2 = srt[i+1], s3 = srt[i+2], s4 = srt[i+3];
            uint2 u1 = HLOAD(s1), u2 = HLOAD(s2), u3 = HLOAD(s3), u4 = HLOAD(s4);
            float al1 = a_s[s1] + ad, al2 = a_s[s2] + ad;
            float al3 = a_s[s3] + ad, al4 = a_s[s4] + ad;
            al1 = (al1 >= 0.f) ? al1 : 0.2f * al1;
            al2 = (al2 >= 0.f) ? al2 : 0.2f * al2;
            al3 = (al3 >= 0.f) ? al3 : 0.2f * al3;
            al4 = (al4 >= 0.f) ? al4 : 0.2f * al4;
            float w1 = __expf(al1), w2 = __expf(al2);
            float w3 = __expf(al3), w4 = __expf(al4);
            a0 = fmaf(w1, UNLO(u1.x), a0); a1 = fmaf(w1, UNHI(u1.x), a1);
            a2 = fmaf(w1, UNLO(u1.y), a2); a3 = fmaf(w1, UNHI(u1.y), a3); den += w1;
            a0 = fmaf(w2, UNLO(u2.x), a0); a1 = fmaf(w2, UNHI(u2.x), a1);
            a2 = fmaf(w2, UNLO(u2.y), a2); a3 = fmaf(w2, UNHI(u2.y), a3); den += w2;
            a0 = fmaf(w3, UNLO(u3.x), a0); a1 = fmaf(w3, UNHI(u3.x), a1);
            a2 = fmaf(w3, UNLO(u3.y), a2); a3 = fmaf(w3, UNHI(u3.y), a3); den += w3;
            a0 = fmaf(w4, UNLO(u4.x), a0); a1 = fmaf(w4, UNHI(u4.x), a1);
            a2 = fmaf(w4, UNLO(u4.y), a2); a3 = fmaf(w4, UNHI(u4.y), a3); den += w4;
        }
        for (; i < e1; ++i) {
            int s1 = srt[i];
            uint2 u1 = HLOAD(s1);
            float al1 = a_s[s1] + ad;
            al1 = (al1 >= 0.f) ? al1 : 0.2f * al1;
            float w1 = __expf(al1);
            a0 = fmaf(w1, UNLO(u1.x), a0); a1 = fmaf(w1, UNHI(u1.x), a1);
            a2 = fmaf(w1, UNLO(u1.y), a2); a3 = fmaf(w1, UNHI(u1.y), a3); den += w1;
        }
        // self-loop
        {
            uint2 u1 = HLOAD(d);
            float al = a_s[d] + ad;
            al = (al >= 0.f) ? al : 0.2f * al;
            float w = __expf(al);
            a0 = fmaf(w, UNLO(u1.x), a0); a1 = fmaf(w, UNHI(u1.x), a1);
            a2 = fmaf(w, UNLO(u1.y), a2); a3 = fmaf(w, UNHI(u1.y), a3); den += w;
        }
        // fused epilogue: /den + bias + relu + threefry dropout, float4 store
        const int t = d * 32 + 4 * j4;
        float rd = 1.0f / den;
        float v0 = fmaxf(a0 * rd + bias[4 * j4],     0.f);
        float v1 = fmaxf(a1 * rd + bias[4 * j4 + 1], 0.f);
        float v2 = fmaxf(a2 * rd + bias[4 * j4 + 2], 0.f);
        float v3 = fmaxf(a3 * rd + bias[4 * j4 + 3], 0.f);
        unsigned p0, q0, p1, q1, p2, q2, p3, q3;
        threefry2x32_01(0u, (unsigned)t,     p0, q0);
        threefry2x32_01(0u, (unsigned)(t+1), p1, q1);
        threefry2x32_01(0u, (unsigned)(t+2), p2, q2);
        threefry2x32_01(0u, (unsigned)(t+3), p3, q3);
        float4 o;
        o.x = ((p0 ^ q0) >> 31) ? 0.f : v0 * 2.f;
        o.y = ((p1 ^ q1) >> 31) ? 0.f : v1 * 2.f;
        o.z = ((p2 ^ q2) >> 31) ? 0.f : v2 * 2.f;
        o.w = ((p3 ^ q3) >> 31) ? 0.f : v3 * 2.f;
        *reinterpret_cast<float4*>(out + t) = o;
    }
#undef HLOAD
#undef UNLO
#undef UNHI
}

extern "C" void kernel_launch(void* const* d_in, const int* in_sizes, int n_in,
                              void* d_out, int out_size, void* d_ws, size_t ws_size,
                              hipStream_t stream) {
    const float* x     = (const float*)d_in[0];
    const float* W     = (const float*)d_in[1];
    const float* att_s = (const float*)d_in[2];
    const float* att_d = (const float*)d_in[3];
    const float* bias  = (const float*)d_in[4];
    const int*   ei    = (const int*)d_in[5];
    float* out = (float*)d_out;

    // ws: Wt16[8192] ushort | packed[EE] uint | h16[NN*32] bf16
    //     | a_s[NN] | a_d[NN] | bhist[512] | gcursor[512] | flag
    unsigned short* Wt16 = (unsigned short*)d_ws;
    unsigned* packed = (unsigned*)(Wt16 + 8192);
    unsigned short* h16 = (unsigned short*)(packed + EE);
    float* a_s = (float*)(h16 + (size_t)NN * FO);
    float* a_d = a_s + NN;
    int* bhist = (int*)(a_d + NN);
    int* gcursor = bhist + NBKT;
    unsigned* flag = (unsigned*)(gcursor + NBKT);

    k_setup<<<1, 256, 0, stream>>>((const unsigned*)ei, W, flag, bhist, gcursor, Wt16);
    k_gemm_hist<<<GEMMB + HISTB, 256, 0, stream>>>(
        x, Wt16, att_s, att_d, h16, a_s, a_d, ei, flag, bhist);
    k_msplit<<<EE / RND, 256, 0, stream>>>(ei, flag, bhist, gcursor, packed);
    k_aggr<<<(NN + DPB - 1) / DPB, 1024, 0, stream>>>(packed, bhist, h16, a_s, a_d, bias, out);
}